// Round 2
// baseline (1515.051 us; speedup 1.0000x reference)
//
#include <hip/hip_runtime.h>
#include <stdint.h>
#include <stddef.h>

// ---------------------------------------------------------------------------
// PCgraph: T=32 steps of
//   mu = tanh(x) @ w^T ; e = (x-mu)*m ; g = e @ w ;
//   x = x - 0.1*m*(e - (1-tanh(x)^2)*g)
// bf16 MFMA 16x16x32, fp32 accum. x state in d_out (fp32).
// Round 11: COUNTED-VMCNT DEEP PIPELINE. Round 10 (256x128 tiles, 2.6x fewer
// staged bytes) was a wash (1415->1487): the loop's __syncthreads drains
// vmcnt(0) INCLUDING the just-issued next-tile loads, so every k-iter pays
// full load-return latency (~2000cy) and at 1 block/CU (96KB LDS) no other
// block covers the stall. Fix (catalog T4): triple-buffer LDS (144KB),
// prefetch depth 2, raw s_barrier + s_waitcnt vmcnt(6) -- the newest 6 loads
// (tile kt+1) stay in flight across the barrier; tile kt+2 is issued AFTER
// the barrier (write-after-read protected by barrier(kt) since its buffer's
// last reader was compute(kt-1)). Per-iter cost drops from load latency to
// max(ds_read ~384cy, MFMA ~307cy, L2/L3 serve). Producers unchanged.
// ws end @ 66,846,720 < 256 MiB (fillBuffer WRITE_SIZE=262144 KB = ws size).
// ---------------------------------------------------------------------------

#define N_DIM 4096
#define B_DIM 256
#define T_STEPS 32
#define LR_X 0.1f
#define N0 768                      // first live column (aligned down from 784)
#define N_LIVE 3328                 // 4096 - 768 = 52*64
#define KSPLIT 8

#define NCH1 64                     // k-chunks in GEMM1 (k over 4096)
#define NCH2 52                     // k-chunks in GEMM2 (k over 3328)

typedef unsigned short ushort_t;
using bf16x8 = __attribute__((ext_vector_type(8))) __bf16;
using f32x4  = __attribute__((ext_vector_type(4))) float;

__device__ __forceinline__ ushort_t f2bf(float f) {
    union { float f; unsigned int u; } v; v.f = f;
    unsigned int r = v.u + 0x7fffu + ((v.u >> 16) & 1u);   // RNE
    return (ushort_t)(r >> 16);
}
__device__ __forceinline__ float bf2f(ushort_t h) {
    union { unsigned int u; float f; } v; v.u = ((unsigned int)h) << 16;
    return v.f;
}

// fragment-order index of element (r, c) inside a 64x64 tile-chunk
// (matches the LDS layout the MFMA fragments read; verified rounds 0-10)
__device__ __forceinline__ int pkidx(int r, int c) {
    const int s = ((r >> 4) << 1) | ((c >> 5) & 1);
    return s * 512 + (r & 15) * 8 + (((c >> 3) & 3) << 7) + (c & 7);
}

__device__ __forceinline__ void async_copy16(const ushort_t* g, ushort_t* l) {
    __builtin_amdgcn_global_load_lds(
        (__attribute__((address_space(1))) void*)(g),
        (__attribute__((address_space(3))) void*)(l),
        16, 0, 0);
}

// --- pack w -> w_pk [52 ntile][64 chunk][4096]  (B of GEMM1: rows 768..4095)
//            -> wt_pk [52 ntile][52 chunk][4096] (B of GEMM2: w^T, live range)
__global__ __launch_bounds__(256) void pack_w(const float* __restrict__ w,
                                              ushort_t* __restrict__ wpk,
                                              ushort_t* __restrict__ wtpk) {
    __shared__ float tile[64][68];
    const int tid = threadIdx.x;
    const int bid = blockIdx.x;
    int row0, col0; ushort_t* dst; bool tr;
    if (bid < 52 * 64) {
        tr   = false;
        dst  = wpk + (size_t)bid * 4096;
        row0 = N0 + (bid >> 6) * 64;      // B-row (n) block
        col0 = (bid & 63) * 64;           // k block
    } else {
        const int b2 = bid - 52 * 64;
        tr   = true;
        dst  = wtpk + (size_t)b2 * 4096;
        const int ntile = b2 / 52, chunk = b2 - ntile * 52;
        row0 = N0 + chunk * 64;           // w-row  = k block (live)
        col0 = N0 + ntile * 64;           // w-col  = n block (live)
    }
    const int rr = tid >> 2, c0 = (tid & 3) * 16;
    const float* src = w + (size_t)(row0 + rr) * N_DIM + col0 + c0;
#pragma unroll
    for (int i = 0; i < 16; i += 4)
        *(float4*)&tile[rr][c0 + i] = *(const float4*)(src + i);
    __syncthreads();
    ushort_t loc[16];
#pragma unroll
    for (int i = 0; i < 16; ++i) {
        const int p = tid * 16 + i;
        const int s = p >> 9, e = p & 511;
        const int r = ((s >> 1) << 4) | ((e >> 3) & 15);
        const int c = ((s & 1) << 5) | (((e >> 7) & 3) << 3) | (e & 7);
        loc[i] = f2bf(tr ? tile[c][r] : tile[r][c]);
    }
    *(uint4*)&dst[tid * 16]     = *(uint4*)&loc[0];
    *(uint4*)&dst[tid * 16 + 8] = *(uint4*)&loc[8];
}

// --- init: x -> d_out (row-major) and t_pk [4 mtile][64 chunk][4096] --------
__global__ __launch_bounds__(256) void pack_t_init(const float* __restrict__ xin,
                                                   float* __restrict__ xout,
                                                   ushort_t* __restrict__ tpk) {
    __shared__ float tile[64][68];
    const int tid  = threadIdx.x;
    const int bid  = blockIdx.x;          // mtile*64 + chunk
    const int row0 = (bid >> 6) * 64;
    const int col0 = (bid & 63) * 64;
    const int rr = tid >> 2, c0 = (tid & 3) * 16;
    const size_t sidx = (size_t)(row0 + rr) * N_DIM + col0 + c0;
#pragma unroll
    for (int i = 0; i < 16; i += 4) {
        float4 v = *(const float4*)(xin + sidx + i);
        *(float4*)(xout + sidx + i) = v;
        tile[rr][c0 + i + 0] = tanhf(v.x);
        tile[rr][c0 + i + 1] = tanhf(v.y);
        tile[rr][c0 + i + 2] = tanhf(v.z);
        tile[rr][c0 + i + 3] = tanhf(v.w);
    }
    __syncthreads();
    ushort_t loc[16];
    ushort_t* dst = tpk + (size_t)bid * 4096;
#pragma unroll
    for (int i = 0; i < 16; ++i) {
        const int p = tid * 16 + i;
        const int s = p >> 9, e = p & 511;
        const int r = ((s >> 1) << 4) | ((e >> 3) & 15);
        const int c = ((s & 1) << 5) | (((e >> 7) & 3) << 3) | (e & 7);
        loc[i] = f2bf(tile[r][c]);
    }
    *(uint4*)&dst[tid * 16]     = *(uint4*)&loc[0];
    *(uint4*)&dst[tid * 16 + 8] = *(uint4*)&loc[8];
}

// --- cvt1 (after GEMM1): mu = sum partials; e -> e_pk (packed, GEMM2 A) -----
__global__ void cvt1(const float* __restrict__ xbuf,
                     const ushort_t* __restrict__ part,
                     ushort_t* __restrict__ epk,
                     const int* __restrict__ mask) {
    const int b  = blockIdx.y;
    const int nl = blockIdx.x * 256 + threadIdx.x;
    const size_t il = (size_t)b * N_LIVE + nl;
    float mu = 0.0f;
#pragma unroll
    for (int z = 0; z < KSPLIT; ++z)
        mu += bf2f(part[(size_t)z * (B_DIM * N_LIVE) + il]);
    const float x = xbuf[(size_t)b * N_DIM + N0 + nl];
    const float e = (x - mu) * (float)mask[N0 + nl];
    epk[((size_t)((b >> 6) * NCH2 + (nl >> 6))) * 4096 + pkidx(b & 63, nl & 63)]
        = f2bf(e);
}

// --- cvt2 (after GEMM2): g = sum partials; x update; refresh t_pk -----------
__global__ void cvt2(float* __restrict__ xbuf,
                     const ushort_t* __restrict__ part,
                     const ushort_t* __restrict__ epk,
                     ushort_t* __restrict__ tpk,
                     const int* __restrict__ mask) {
    const int b  = blockIdx.y;
    const int nl = blockIdx.x * 256 + threadIdx.x;
    const size_t ix = (size_t)b * N_DIM + N0 + nl;
    float g = 0.0f;
#pragma unroll
    for (int z = 0; z < KSPLIT; ++z)
        g += bf2f(part[(size_t)z * (B_DIM * N_LIVE) + (size_t)b * N_LIVE + nl]);
    const float x  = xbuf[ix];
    const float th = tanhf(x);
    const float e  = bf2f(epk[((size_t)((b >> 6) * NCH2 + (nl >> 6))) * 4096
                              + pkidx(b & 63, nl & 63)]);
    const float m  = (float)mask[N0 + nl];
    const float xn = x - LR_X * m * (e - (1.0f - th * th) * g);
    xbuf[ix] = xn;
    const int k = N0 + nl;
    tpk[((size_t)((b >> 6) * NCH1 + (k >> 6))) * 4096 + pkidx(b & 63, k & 63)]
        = f2bf(tanhf(xn));
}

// --- split-K GEMM, BM=256 x BN=128, triple-buffered counted-vmcnt pipeline --
// Apk: [4 mtile][NCH][4096], Bpk: [52 ntile][NCH][4096].
// Block = (ntile-pair nt2, z). Per k-iter it streams 6 linear 8KB chunks (4 A
// mtile-chunks + 2 B ntile-chunks) = 48 wave-instructions of 1KB each.
// Pipeline: prefetch depth 2, 3 LDS buffers. Loop body:
//   s_waitcnt vmcnt(6)   <- tile kt landed; tile kt+1's 6 loads stay in flight
//   s_barrier            <- all waves' tile-kt data visible
//   stage(kt+2)          <- safe: buf[(kt+2)%3]'s last reader compute(kt-1)
//                           finished before this barrier
//   compute(kt)
// Never drains vmcnt to 0 in the main loop (T4).
template <int NCH>
__global__ __launch_bounds__(512) void gemm_big(
    const ushort_t* __restrict__ Apk,
    const ushort_t* __restrict__ Bpk,
    ushort_t* __restrict__ part) {
    __shared__ __align__(16) ushort_t As[3][4 * 4096];   // 96 KB
    __shared__ __align__(16) ushort_t Bs[3][2 * 4096];   // 48 KB

    const int tid    = threadIdx.x;
    const int lane   = tid & 63;
    const int wid    = tid >> 6;       // 0..7
    const int wave_m = wid >> 1;       // 0..3  -> 64-row band (= mtile)
    const int wave_n = wid & 1;        // 0..1  -> 64-col band (= ntile within pair)
    const int nt2    = blockIdx.x;     // 0..25 (ntile pair)
    const int z      = blockIdx.z;

    // uneven split-K: NCH=64 -> 8x8; NCH=52 -> 4x7 + 4x6
    const int base   = NCH / KSPLIT, rem = NCH % KSPLIT;
    const int kiters = base + (z < rem ? 1 : 0);
    const int chbase = z * base + (z < rem ? z : rem);

    ushort_t* pout = part + (size_t)z * (B_DIM * N_LIVE);

    const ushort_t* Ab = Apk + (size_t)chbase * 4096;
    const ushort_t* Bb = Bpk + ((size_t)(nt2 * 2) * NCH + chbase) * 4096;
    const int t8 = tid * 8;            // 16B per thread per chunk

    auto stage = [&](int buf, int kt) {
#pragma unroll
        for (int mt = 0; mt < 4; ++mt)
            async_copy16(Ab + ((size_t)mt * NCH + kt) * 4096 + t8,
                         &As[buf][mt * 4096 + t8]);
#pragma unroll
        for (int u = 0; u < 2; ++u)
            async_copy16(Bb + ((size_t)u * NCH + kt) * 4096 + t8,
                         &Bs[buf][u * 4096 + t8]);
    };

    f32x4 acc[4][4] = {};

    auto compute = [&](int buf) {
#pragma unroll
        for (int ks = 0; ks < 2; ++ks) {
            bf16x8 a[4], b[4];
#pragma unroll
            for (int i = 0; i < 4; ++i)
                a[i] = *(const bf16x8*)(&As[buf][wave_m * 4096
                                                 + (i * 2 + ks) * 512 + lane * 8]);
#pragma unroll
            for (int j = 0; j < 4; ++j)
                b[j] = *(const bf16x8*)(&Bs[buf][wave_n * 4096
                                                 + (j * 2 + ks) * 512 + lane * 8]);
#pragma unroll
            for (int i = 0; i < 4; ++i)
#pragma unroll
                for (int j = 0; j < 4; ++j)
                    acc[i][j] = __builtin_amdgcn_mfma_f32_16x16x32_bf16(
                        a[i], b[j], acc[i][j], 0, 0, 0);
        }
    };

    // prologue: prefetch tiles 0 and 1 (kiters >= 6 always)
    stage(0, 0);
    stage(1, 1);

    for (int kt = 0; kt < kiters; ++kt) {
        // need tile kt landed; keep tile kt+1's 6 loads in flight
        if (kt + 1 < kiters) asm volatile("s_waitcnt vmcnt(6)" ::: "memory");
        else                 asm volatile("s_waitcnt vmcnt(0)" ::: "memory");
        __builtin_amdgcn_s_barrier();
        asm volatile("" ::: "memory");   // pin ds_reads below the barrier
        if (kt + 2 < kiters) stage((kt + 2) % 3, kt + 2);
        compute(kt % 3);
    }

    // Epilogue: bf16 partial stores (row-major partials). No LDS use -> no
    // trailing barrier needed; vmcnt is 0 after the last iteration's wait.
    // C/D layout (verified m89/m91): col = lane&15, row = quad*4+reg
    const int l15  = lane & 15;
    const int quad = lane >> 4;
#pragma unroll
    for (int j = 0; j < 4; ++j) {
        const int nl = nt2 * 128 + wave_n * 64 + j * 16 + l15;
#pragma unroll
        for (int i = 0; i < 4; ++i) {
#pragma unroll
            for (int r = 0; r < 4; ++r) {
                const int m = wave_m * 64 + i * 16 + quad * 4 + r;
                pout[(size_t)m * N_LIVE + nl] = f2bf(acc[i][j][r]);
            }
        }
    }
}

extern "C" void kernel_launch(void* const* d_in, const int* in_sizes, int n_in,
                              void* d_out, int out_size, void* d_ws, size_t ws_size,
                              hipStream_t stream) {
    const float* x_in  = (const float*)d_in[0];
    const float* w_in  = (const float*)d_in[1];
    const int*   mask  = (const int*)d_in[2];
    float*       xbuf  = (float*)d_out;          // state lives in d_out

    uint8_t* ws = (uint8_t*)d_ws;
    // ws layout (end @ 66,846,720 bytes; ws_size = 256 MiB per fillBuffer):
    ushort_t* w_pk  = (ushort_t*)(ws);                   // 52*64*4096*2 = 27,262,976
    ushort_t* wt_pk = (ushort_t*)(ws + 27262976);        // 52*52*4096*2 = 22,151,168
    ushort_t* t_pk  = (ushort_t*)(ws + 49414144);        //  4*64*4096*2 =  2,097,152
    ushort_t* e_pk  = (ushort_t*)(ws + 51511296);        //  4*52*4096*2 =  1,703,936
    ushort_t* part  = (ushort_t*)(ws + 53215232);        // 8*256*3328*2 = 13,631,488

    pack_w<<<dim3(52 * 64 + 52 * 52), 256, 0, stream>>>(w_in, w_pk, wt_pk);
    pack_t_init<<<dim3(4 * 64), 256, 0, stream>>>(x_in, xbuf, t_pk);

    const dim3 ggrid(N_LIVE / 128, 1, KSPLIT);   // 26 x 1 x 8 = 208 blocks
    const dim3 cgrid(N_LIVE / 256, B_DIM);
    for (int t = 0; t < T_STEPS; ++t) {
        // GEMM1: part[z] = mu partial ; A = t_pk (64 chunks), B = w_pk
        gemm_big<NCH1><<<ggrid, 512, 0, stream>>>(t_pk, w_pk, part);
        cvt1<<<cgrid, 256, 0, stream>>>(xbuf, part, e_pk, mask);
        // GEMM2: part[z] = g partial ; A = e_pk (52 chunks), B = wt_pk
        gemm_big<NCH2><<<ggrid, 512, 0, stream>>>(e_pk, wt_pk, part);
        cvt2<<<cgrid, 256, 0, stream>>>(xbuf, part, e_pk, t_pk, mask);
    }
}

// Round 3
// 1321.297 us; speedup vs baseline: 1.1466x; 1.1466x over previous
//
#include <hip/hip_runtime.h>
#include <stdint.h>
#include <stddef.h>

// ---------------------------------------------------------------------------
// PCgraph: T=32 steps of
//   mu = tanh(x) @ w^T ; e = (x-mu)*m ; g = e @ w ;
//   x = x - 0.1*m*(e - (1-tanh(x)^2)*g)
// bf16 MFMA 16x16x32, fp32 accum. x state in d_out (fp32).
// Round 12: back to the PROVEN r9 structure (64x64 tiles, 4-wave blocks,
// KSPLIT=4, ~3.5 blocks/CU -- 1415us), plus two orthogonal levers:
//  (1) mu0 precompute: sensory x (cols 0..767) is clamped, so
//      tanh(x)@w^T over k<768 is CONSTANT across steps. Precompute once
//      (gemm_mu0, fp32 out); per-step GEMM1 k shrinks 4096->3328. Both
//      GEMMs become identical 52-chunk geometry (13 kiters at KSPLIT=4).
//  (2) XCD-pinned B panels: 1-D grid + bijective decode so ALL blocks of a
//      given ntile land on one XCD (xcd = bid&7 round-robin). Per-XCD B
//      footprint = 7 ntiles x 52 chunks x 8KB = 2.9MB < 4MiB L2, and the
//      map is dispatch-stable so w stays L2-warm across all 32 steps.
//      Rationale (r10/r11 post-mortem): per-wave global_load_lds fill is
//      ~1KB per round-trip latency; pipelining depth didn't help, so cut
//      the LATENCY (L3 ~700cy -> L2 ~250cy) and keep wave count high.
// ws end @ 63,438,848 < 256 MiB (fillBuffer WRITE_SIZE=262144 KB = ws size).
// ---------------------------------------------------------------------------

#define N_DIM 4096
#define B_DIM 256
#define T_STEPS 32
#define LR_X 0.1f
#define N0 768                      // first live column (aligned down from 784)
#define N_LIVE 3328                 // 4096 - 768 = 52*64
#define KSPLIT 4
#define NCHL 52                     // live k-chunks (both GEMMs)
#define KITERS 13                   // 52 / 4

typedef unsigned short ushort_t;
using bf16x8 = __attribute__((ext_vector_type(8))) __bf16;
using f32x4  = __attribute__((ext_vector_type(4))) float;

__device__ __forceinline__ ushort_t f2bf(float f) {
    union { float f; unsigned int u; } v; v.f = f;
    unsigned int r = v.u + 0x7fffu + ((v.u >> 16) & 1u);   // RNE
    return (ushort_t)(r >> 16);
}
__device__ __forceinline__ float bf2f(ushort_t h) {
    union { unsigned int u; float f; } v; v.u = ((unsigned int)h) << 16;
    return v.f;
}

// fragment-order index of element (r, c) inside a 64x64 tile-chunk
// (matches the LDS layout the MFMA fragments read; verified rounds 0-11)
__device__ __forceinline__ int pkidx(int r, int c) {
    const int s = ((r >> 4) << 1) | ((c >> 5) & 1);
    return s * 512 + (r & 15) * 8 + (((c >> 3) & 3) << 7) + (c & 7);
}

__device__ __forceinline__ void async_copy16(const ushort_t* g, ushort_t* l) {
    __builtin_amdgcn_global_load_lds(
        (__attribute__((address_space(1))) void*)(g),
        (__attribute__((address_space(3))) void*)(l),
        16, 0, 0);
}

// --- pack w -> w_pk [52 ntile][64 chunk][4096]  (B of GEMM1: rows 768..4095)
//            -> wt_pk [52 ntile][52 chunk][4096] (B of GEMM2: w^T, live range)
__global__ __launch_bounds__(256) void pack_w(const float* __restrict__ w,
                                              ushort_t* __restrict__ wpk,
                                              ushort_t* __restrict__ wtpk) {
    __shared__ float tile[64][68];
    const int tid = threadIdx.x;
    const int bid = blockIdx.x;
    int row0, col0; ushort_t* dst; bool tr;
    if (bid < 52 * 64) {
        tr   = false;
        dst  = wpk + (size_t)bid * 4096;
        row0 = N0 + (bid >> 6) * 64;      // B-row (n) block
        col0 = (bid & 63) * 64;           // k block
    } else {
        const int b2 = bid - 52 * 64;
        tr   = true;
        dst  = wtpk + (size_t)b2 * 4096;
        const int ntile = b2 / 52, chunk = b2 - ntile * 52;
        row0 = N0 + chunk * 64;           // w-row  = k block (live)
        col0 = N0 + ntile * 64;           // w-col  = n block (live)
    }
    const int rr = tid >> 2, c0 = (tid & 3) * 16;
    const float* src = w + (size_t)(row0 + rr) * N_DIM + col0 + c0;
#pragma unroll
    for (int i = 0; i < 16; i += 4)
        *(float4*)&tile[rr][c0 + i] = *(const float4*)(src + i);
    __syncthreads();
    ushort_t loc[16];
#pragma unroll
    for (int i = 0; i < 16; ++i) {
        const int p = tid * 16 + i;
        const int s = p >> 9, e = p & 511;
        const int r = ((s >> 1) << 4) | ((e >> 3) & 15);
        const int c = ((s & 1) << 5) | (((e >> 7) & 3) << 3) | (e & 7);
        loc[i] = f2bf(tr ? tile[c][r] : tile[r][c]);
    }
    *(uint4*)&dst[tid * 16]     = *(uint4*)&loc[0];
    *(uint4*)&dst[tid * 16 + 8] = *(uint4*)&loc[8];
}

// --- init: x -> d_out (row-major) and t_pk [4 mtile][64 chunk][4096] --------
__global__ __launch_bounds__(256) void pack_t_init(const float* __restrict__ xin,
                                                   float* __restrict__ xout,
                                                   ushort_t* __restrict__ tpk) {
    __shared__ float tile[64][68];
    const int tid  = threadIdx.x;
    const int bid  = blockIdx.x;          // mtile*64 + chunk
    const int row0 = (bid >> 6) * 64;
    const int col0 = (bid & 63) * 64;
    const int rr = tid >> 2, c0 = (tid & 3) * 16;
    const size_t sidx = (size_t)(row0 + rr) * N_DIM + col0 + c0;
#pragma unroll
    for (int i = 0; i < 16; i += 4) {
        float4 v = *(const float4*)(xin + sidx + i);
        *(float4*)(xout + sidx + i) = v;
        tile[rr][c0 + i + 0] = tanhf(v.x);
        tile[rr][c0 + i + 1] = tanhf(v.y);
        tile[rr][c0 + i + 2] = tanhf(v.z);
        tile[rr][c0 + i + 3] = tanhf(v.w);
    }
    __syncthreads();
    ushort_t loc[16];
    ushort_t* dst = tpk + (size_t)bid * 4096;
#pragma unroll
    for (int i = 0; i < 16; ++i) {
        const int p = tid * 16 + i;
        const int s = p >> 9, e = p & 511;
        const int r = ((s >> 1) << 4) | ((e >> 3) & 15);
        const int c = ((s & 1) << 5) | (((e >> 7) & 3) << 3) | (e & 7);
        loc[i] = f2bf(tile[r][c]);
    }
    *(uint4*)&dst[tid * 16]     = *(uint4*)&loc[0];
    *(uint4*)&dst[tid * 16 + 8] = *(uint4*)&loc[8];
}

// --- one-time: mu0 = tanh(x_sensory) @ w_sensory^T  (k = chunks 0..11) ------
__global__ __launch_bounds__(256) void gemm_mu0(const ushort_t* __restrict__ Apk,
                                                const ushort_t* __restrict__ Bpk,
                                                float* __restrict__ mu0) {
    __shared__ __align__(16) ushort_t As[2][4096];
    __shared__ __align__(16) ushort_t Bs[2][4096];
    const int tid  = threadIdx.x;
    const int lane = tid & 63;
    const int wid  = tid >> 6;
    const int wave_m = wid >> 1, wave_n = wid & 1;
    const int ntile = blockIdx.x, mtile = blockIdx.y;

    const ushort_t* Ab = Apk + (size_t)mtile * 64 * 4096;
    const ushort_t* Bb = Bpk + (size_t)ntile * 64 * 4096;

    auto stage = [&](int buf, int kt) {
#pragma unroll
        for (int u = 0; u < 2; ++u) {
            const int off = (wid * 2 + u) * 512 + lane * 8;
            async_copy16(Ab + (size_t)kt * 4096 + off, &As[buf][off]);
            async_copy16(Bb + (size_t)kt * 4096 + off, &Bs[buf][off]);
        }
    };
    f32x4 acc[2][2] = {};
    auto compute = [&](int buf) {
#pragma unroll
        for (int ks = 0; ks < 2; ++ks) {
            bf16x8 a[2], b[2];
#pragma unroll
            for (int i = 0; i < 2; ++i) {
                const int asub = (wave_m * 2 + i) * 2 + ks;
                const int bsub = (wave_n * 2 + i) * 2 + ks;
                a[i] = *(const bf16x8*)(&As[buf][asub * 512 + lane * 8]);
                b[i] = *(const bf16x8*)(&Bs[buf][bsub * 512 + lane * 8]);
            }
#pragma unroll
            for (int i = 0; i < 2; ++i)
#pragma unroll
                for (int j = 0; j < 2; ++j)
                    acc[i][j] = __builtin_amdgcn_mfma_f32_16x16x32_bf16(
                        a[i], b[j], acc[i][j], 0, 0, 0);
        }
    };
    stage(0, 0);
    __syncthreads();
    for (int kt = 0; kt < 12; ++kt) {          // sensory chunks 0..11
        if (kt + 1 < 12) stage((kt + 1) & 1, kt + 1);
        compute(kt & 1);
        __syncthreads();
    }
    const int l15 = lane & 15, quad = lane >> 4;
#pragma unroll
    for (int j = 0; j < 2; ++j) {
        const int nl = ntile * 64 + wave_n * 32 + j * 16 + l15;
#pragma unroll
        for (int i = 0; i < 2; ++i)
#pragma unroll
            for (int r = 0; r < 4; ++r) {
                const int m = mtile * 64 + wave_m * 32 + i * 16 + quad * 4 + r;
                mu0[(size_t)m * N_LIVE + nl] = acc[i][j][r];
            }
    }
}

// --- cvt1 (after GEMM1): mu = mu0 + sum partials; e -> e_pk (GEMM2 A) -------
__global__ void cvt1(const float* __restrict__ xbuf,
                     const ushort_t* __restrict__ part,
                     const float* __restrict__ mu0,
                     ushort_t* __restrict__ epk,
                     const int* __restrict__ mask) {
    const int b  = blockIdx.y;
    const int nl = blockIdx.x * 256 + threadIdx.x;
    const size_t il = (size_t)b * N_LIVE + nl;
    float mu = mu0[il];
#pragma unroll
    for (int z = 0; z < KSPLIT; ++z)
        mu += bf2f(part[(size_t)z * (B_DIM * N_LIVE) + il]);
    const float x = xbuf[(size_t)b * N_DIM + N0 + nl];
    const float e = (x - mu) * (float)mask[N0 + nl];
    epk[((size_t)((b >> 6) * NCHL + (nl >> 6))) * 4096 + pkidx(b & 63, nl & 63)]
        = f2bf(e);
}

// --- cvt2 (after GEMM2): g = sum partials; x update; refresh t_pk -----------
__global__ void cvt2(float* __restrict__ xbuf,
                     const ushort_t* __restrict__ part,
                     const ushort_t* __restrict__ epk,
                     ushort_t* __restrict__ tpk,
                     const int* __restrict__ mask) {
    const int b  = blockIdx.y;
    const int nl = blockIdx.x * 256 + threadIdx.x;
    const size_t ix = (size_t)b * N_DIM + N0 + nl;
    float g = 0.0f;
#pragma unroll
    for (int z = 0; z < KSPLIT; ++z)
        g += bf2f(part[(size_t)z * (B_DIM * N_LIVE) + (size_t)b * N_LIVE + nl]);
    const float x  = xbuf[ix];
    const float th = tanhf(x);
    const float e  = bf2f(epk[((size_t)((b >> 6) * NCHL + (nl >> 6))) * 4096
                              + pkidx(b & 63, nl & 63)]);
    const float m  = (float)mask[N0 + nl];
    const float xn = x - LR_X * m * (e - (1.0f - th * th) * g);
    xbuf[ix] = xn;
    const int k = N0 + nl;                    // live k chunk = 12 + (nl>>6)
    tpk[((size_t)((b >> 6) * 64 + (k >> 6))) * 4096 + pkidx(b & 63, k & 63)]
        = f2bf(tanhf(xn));
}

// --- split-K GEMM, 64x64 tiles, XCD-pinned ntiles ---------------------------
// Apk: [4 mtile][SA chunk][4096], Bpk: [52 ntile][SB chunk][4096].
// 1-D grid of 896; xcd = bid&7 (dispatch round-robin), i = bid>>3.
// xcd<4 own 7 ntiles (n0=xcd*7), xcd>=4 own 6 (n0=28+(xcd-4)*6); slots per
// ntile = 4 mtile x 4 z = 16; surplus slots return early. All blocks of an
// ntile share one XCD -> B panel (52x8KB=416KB x <=7 = 2.9MB) is L2-resident
// and stays warm across the 32 steps (stable map). k-chunks used:
// CO..CO+51 (CO=12 skips sensory chunks for GEMM1 over t_pk/w_pk).
template <int SA, int SB, int CO>
__global__ __launch_bounds__(256) void gemm_split(
    const ushort_t* __restrict__ Apk,
    const ushort_t* __restrict__ Bpk,
    ushort_t* __restrict__ part) {
    __shared__ __align__(16) ushort_t As[2][4096];   // 8 KB x2
    __shared__ __align__(16) ushort_t Bs[2][4096];   // 8 KB x2

    const int bid = blockIdx.x;
    const int xcd = bid & 7;
    const int i   = bid >> 3;                 // 0..111
    const int nloc = (xcd < 4) ? 7 : 6;
    if (i >= nloc * 16) return;
    const int n0    = (xcd < 4) ? xcd * 7 : 28 + (xcd - 4) * 6;
    const int ntile = n0 + (i >> 4);
    const int mtile = (i >> 2) & 3;
    const int z     = i & 3;

    const int tid    = threadIdx.x;
    const int lane   = tid & 63;
    const int wid    = tid >> 6;       // 0..3
    const int wave_m = wid >> 1;
    const int wave_n = wid & 1;
    const int chbase = CO + z * KITERS;

    ushort_t* pout = part + (size_t)z * (B_DIM * N_LIVE);
    const ushort_t* Ab = Apk + ((size_t)mtile * SA + chbase) * 4096;
    const ushort_t* Bb = Bpk + ((size_t)ntile * SB + chbase) * 4096;

    auto stage = [&](int buf, int kt) {
#pragma unroll
        for (int u = 0; u < 2; ++u) {
            const int off = (wid * 2 + u) * 512 + lane * 8;
            async_copy16(Ab + (size_t)kt * 4096 + off, &As[buf][off]);
            async_copy16(Bb + (size_t)kt * 4096 + off, &Bs[buf][off]);
        }
    };

    f32x4 acc[2][2] = {};

    auto compute = [&](int buf) {
#pragma unroll
        for (int ks = 0; ks < 2; ++ks) {
            bf16x8 a[2], b[2];
#pragma unroll
            for (int i2 = 0; i2 < 2; ++i2) {
                const int asub = (wave_m * 2 + i2) * 2 + ks;
                const int bsub = (wave_n * 2 + i2) * 2 + ks;
                a[i2] = *(const bf16x8*)(&As[buf][asub * 512 + lane * 8]);
                b[i2] = *(const bf16x8*)(&Bs[buf][bsub * 512 + lane * 8]);
            }
#pragma unroll
            for (int i2 = 0; i2 < 2; ++i2)
#pragma unroll
                for (int j = 0; j < 2; ++j)
                    acc[i2][j] = __builtin_amdgcn_mfma_f32_16x16x32_bf16(
                        a[i2], b[j], acc[i2][j], 0, 0, 0);
        }
    };

    stage(0, 0);
    __syncthreads();
    for (int kt = 0; kt < KITERS; ++kt) {
        if (kt + 1 < KITERS) stage((kt + 1) & 1, kt + 1);
        compute(kt & 1);
        __syncthreads();
    }

    // Epilogue: bf16 partial stores (row-major partials).
    // C/D layout (verified m89/m91): col = lane&15, row = quad*4+reg
    const int l15  = lane & 15;
    const int quad = lane >> 4;
#pragma unroll
    for (int j = 0; j < 2; ++j) {
        const int nl = ntile * 64 + wave_n * 32 + j * 16 + l15;
#pragma unroll
        for (int i2 = 0; i2 < 2; ++i2) {
#pragma unroll
            for (int r = 0; r < 4; ++r) {
                const int m = mtile * 64 + wave_m * 32 + i2 * 16 + quad * 4 + r;
                pout[(size_t)m * N_LIVE + nl] = f2bf(acc[i2][j][r]);
            }
        }
    }
}

extern "C" void kernel_launch(void* const* d_in, const int* in_sizes, int n_in,
                              void* d_out, int out_size, void* d_ws, size_t ws_size,
                              hipStream_t stream) {
    const float* x_in  = (const float*)d_in[0];
    const float* w_in  = (const float*)d_in[1];
    const int*   mask  = (const int*)d_in[2];
    float*       xbuf  = (float*)d_out;          // state lives in d_out

    uint8_t* ws = (uint8_t*)d_ws;
    // ws layout (end @ 63,438,848 bytes; ws_size = 256 MiB per fillBuffer):
    ushort_t* w_pk  = (ushort_t*)(ws);                   // 52*64*4096*2 = 27,262,976
    ushort_t* wt_pk = (ushort_t*)(ws + 27262976);        // 52*52*4096*2 = 22,151,168
    ushort_t* t_pk  = (ushort_t*)(ws + 49414144);        //  4*64*4096*2 =  2,097,152
    ushort_t* e_pk  = (ushort_t*)(ws + 51511296);        //  4*52*4096*2 =  1,703,936
    ushort_t* part  = (ushort_t*)(ws + 53215232);        // 4*256*3328*2 =  6,815,744
    float*    mu0   = (float*)(ws + 60030976);           //  256*3328*4  =  3,407,872

    pack_w<<<dim3(52 * 64 + 52 * 52), 256, 0, stream>>>(w_in, w_pk, wt_pk);
    pack_t_init<<<dim3(4 * 64), 256, 0, stream>>>(x_in, xbuf, t_pk);
    gemm_mu0<<<dim3(52, 4), 256, 0, stream>>>(t_pk, w_pk, mu0);

    const dim3 cgrid(N_LIVE / 256, B_DIM);
    for (int t = 0; t < T_STEPS; ++t) {
        // GEMM1: part[z] = mu_live partial ; A = t_pk (chunks 12..63), B = w_pk
        gemm_split<64, 64, 12><<<896, 256, 0, stream>>>(t_pk, w_pk, part);
        cvt1<<<cgrid, 256, 0, stream>>>(xbuf, part, mu0, e_pk, mask);
        // GEMM2: part[z] = g partial ; A = e_pk (52 chunks), B = wt_pk
        gemm_split<52, 52, 0><<<896, 256, 0, stream>>>(e_pk, wt_pk, part);
        cvt2<<<cgrid, 256, 0, stream>>>(xbuf, part, e_pk, t_pk, mask);
    }
}